// Round 3
// baseline (4575.726 us; speedup 1.0000x reference)
//
#include <hip/hip_runtime.h>
#include <hip/hip_bf16.h>

#define BB 256
#define TT 512
#define XS 40
#define HS 128
#define GS 512  // 4*HS
#define BSUB 16

typedef __attribute__((ext_vector_type(8))) short bf16x8;
typedef __attribute__((ext_vector_type(4))) float f32x4;

enum { MODE_PROJ = 0, MODE_FLAT = 1, MODE_CONCAT = 2 };

__device__ __forceinline__ float fast_sigmoid(float x) {
    return __frcp_rn(1.0f + __expf(-x));
}
__device__ __forceinline__ float fast_tanh(float x) {
    x = fminf(fmaxf(x, -15.0f), 15.0f);
    float e = __expf(2.0f * x);
    return (e - 1.0f) * __frcp_rn(e + 1.0f);
}
__device__ __forceinline__ ushort f2bf(float f) {  // RNE float->bf16 bits
    uint u = __float_as_uint(f);
    u = u + 0x7FFFu + ((u >> 16) & 1u);
    return (ushort)(u >> 16);
}
__device__ __forceinline__ float bf2f(ushort h) {
    return __uint_as_float(((uint)h) << 16);
}

// ---------------- fp32 tile GEMM (unchanged from round 2, validated) ----------------
template <int K, int KC, int NS, int MODE, bool RELU>
__global__ __launch_bounds__(256) void gemm2(
    const float* __restrict__ A, const float* __restrict__ A2,
    const float* __restrict__ W, const float* __restrict__ b1p,
    const float* __restrict__ b2p, float* __restrict__ out,
    int Tc, int t0, int ooff) {
    __shared__ float at[KC][132];
    __shared__ float wt[KC][68];
    const int tid = threadIdx.x;
    const int row0 = blockIdx.x * 128;
    const int n0 = blockIdx.y * 64;
    const int tx = tid & 15;
    const int ty = tid >> 4;

    float acc[8][4] = {};

    for (int c0 = 0; c0 < K; c0 += KC) {
        for (int idx = tid; idx < 128 * KC; idx += 256) {
            int r = idx / KC, c = idx - r * KC;
            int cg = c0 + c;
            int m = row0 + r;
            float v;
            if (MODE == MODE_PROJ) {
                int b = m / Tc, tt = m - b * Tc;
                v = A[(size_t)(b * TT + t0 + tt) * K + cg];
            } else if (MODE == MODE_FLAT) {
                v = A[(size_t)(m + t0) * K + cg];
            } else {
                int mg = m + t0;
                v = (cg < XS) ? A[(size_t)mg * XS + cg] : A2[(size_t)mg * HS + (cg - XS)];
            }
            at[c][r] = v;
        }
        for (int idx = tid; idx < 64 * KC; idx += 256) {
            int r = idx / KC, c = idx - r * KC;
            wt[c][r] = W[(size_t)(n0 + r) * K + c0 + c];
        }
        __syncthreads();

#pragma unroll 4
        for (int k = 0; k < KC; ++k) {
            float4 a0 = *(const float4*)&at[k][ty * 8];
            float4 a1 = *(const float4*)&at[k][ty * 8 + 4];
            float4 wv = *(const float4*)&wt[k][tx * 4];
            float av[8] = {a0.x, a0.y, a0.z, a0.w, a1.x, a1.y, a1.z, a1.w};
            float wj[4] = {wv.x, wv.y, wv.z, wv.w};
#pragma unroll
            for (int i = 0; i < 8; i++)
#pragma unroll
                for (int j = 0; j < 4; j++) acc[i][j] = fmaf(av[i], wj[j], acc[i][j]);
        }
        __syncthreads();
    }

    float4 bv = *(const float4*)&b1p[n0 + tx * 4];
    if (MODE == MODE_PROJ) {
        float4 b2v = *(const float4*)&b2p[n0 + tx * 4];
        bv.x += b2v.x; bv.y += b2v.y; bv.z += b2v.z; bv.w += b2v.w;
    }
#pragma unroll
    for (int i = 0; i < 8; i++) {
        int m = row0 + ty * 8 + i;
        size_t obase = (MODE == MODE_PROJ) ? (size_t)m * NS : (size_t)(m + ooff) * NS;
        float4 o;
        o.x = acc[i][0] + bv.x; o.y = acc[i][1] + bv.y;
        o.z = acc[i][2] + bv.z; o.w = acc[i][3] + bv.w;
        if (RELU) {
            o.x = fmaxf(o.x, 0.f); o.y = fmaxf(o.y, 0.f);
            o.z = fmaxf(o.z, 0.f); o.w = fmaxf(o.w, 0.f);
        }
        *(float4*)&out[obase + n0 + tx * 4] = o;
    }
}

// ---------------- MFMA recurrence ----------------
// Grid: B/16 blocks, 512 threads (8 waves). Block owns 16 batch rows.
// Wave w owns gates [w*64, w*64+64): 4 n-tiles of 16.
// D = A*B: A = h_aug [16 rows x K], B = Whh^T slices (resident VGPR frags).
// 3-product bf16 split: h_hi*W_hi + h_lo*W_hi + h_hi*W_lo  (~fp32 accuracy).
// mfma_f32_16x16x32_bf16 layouts: a[e]=A[l&15][8*(l>>4)+e], b[e]=B[8*(l>>4)+e][l&15],
// d[e]=D[4*(l>>4)+e][l&15]  (rows of D = batch rows, cols = gates).
__global__ __launch_bounds__(512, 2) void lstm_rec3(
    const float* __restrict__ Whh, const float* __restrict__ xW,
    const float* __restrict__ h0, const float* __restrict__ c0,
    float* __restrict__ hstate, float* __restrict__ cstate,
    float* __restrict__ y, int Tc, int t0) {
    __shared__ __align__(16) ushort h_aug[BSUB][264];  // [r][0:128]=hi, [128:256]=lo, pad 8
    __shared__ float act[BSUB][516];                   // activated gates, padded stride
    const int tid = threadIdx.x;
    const int w = tid >> 6, l = tid & 63;
    const int lr = l & 15;   // frag row/col index
    const int lk = l >> 4;   // k sub-block
    const int b0 = blockIdx.x * BSUB;
    const int gbase = w * 64;
    const int gtype = w >> 1;  // 0=i 1=f 2=g(tanh) 3=o, wave-uniform

    // ---- persistent weight fragments: bhi/blo[nt][q] ----
    bf16x8 bhi[4][4], blo[4][4];
#pragma unroll
    for (int nt = 0; nt < 4; nt++) {
        const float* wrow = Whh + (size_t)(gbase + nt * 16 + lr) * HS;
#pragma unroll
        for (int q = 0; q < 4; q++) {
            const float4* p = (const float4*)(wrow + q * 32 + lk * 8);
            float4 v0 = p[0], v1 = p[1];
            float vv[8] = {v0.x, v0.y, v0.z, v0.w, v1.x, v1.y, v1.z, v1.w};
            bf16x8 h8, l8;
#pragma unroll
            for (int e = 0; e < 8; e++) {
                ushort hb = f2bf(vv[e]);
                h8[e] = (short)hb;
                l8[e] = (short)f2bf(vv[e] - bf2f(hb));
            }
            bhi[nt][q] = h8;
            blo[nt][q] = l8;
        }
    }

    // ---- state init (phase-B thread mapping: u = unit, rows q4*4+p) ----
    const int u = tid & 127, q4 = tid >> 7;
    float c[4];
#pragma unroll
    for (int p = 0; p < 4; p++) {
        int r = q4 * 4 + p;
        float hv, cv;
        if (t0 == 0) {
            hv = h0[(size_t)(b0 + r) * HS + u];
            cv = c0[(size_t)(b0 + r) * HS + u];
        } else {
            hv = hstate[(size_t)(b0 + r) * HS + u];
            cv = cstate[(size_t)(b0 + r) * HS + u];
        }
        c[p] = cv;
        ushort hb = f2bf(hv);
        h_aug[r][u] = hb;
        h_aug[r][128 + u] = f2bf(hv - bf2f(hb));
    }

    // ---- xW prefetch setup: thread handles (nt,e): row b0+4*lk+e, gate gbase+nt*16+lr
    const size_t rowstride = (size_t)Tc * GS;
    const float* xwb = xW + (size_t)(b0 + 4 * lk) * rowstride + gbase + lr;
    float cur[16], nxt[16];
#pragma unroll
    for (int nt = 0; nt < 4; nt++)
#pragma unroll
        for (int e = 0; e < 4; e++)
            cur[nt * 4 + e] = xwb[e * rowstride + nt * 16];  // t = 0
    __syncthreads();

    for (int t = 0; t < Tc; ++t) {
        // prefetch xW for t+1 (clamped so count stays uniform)
        int tn = (t + 1 < Tc) ? t + 1 : t;
        const float* xwt = xwb + (size_t)tn * GS;
#pragma unroll
        for (int nt = 0; nt < 4; nt++)
#pragma unroll
            for (int e = 0; e < 4; e++)
                nxt[nt * 4 + e] = xwt[e * rowstride + nt * 16];

        // gates = xW + h.Whh^T  via MFMA (3-product split)
        f32x4 acc0 = {cur[0], cur[1], cur[2], cur[3]};
        f32x4 acc1 = {cur[4], cur[5], cur[6], cur[7]};
        f32x4 acc2 = {cur[8], cur[9], cur[10], cur[11]};
        f32x4 acc3 = {cur[12], cur[13], cur[14], cur[15]};
#pragma unroll
        for (int q = 0; q < 4; q++) {
            bf16x8 ah = *(const bf16x8*)&h_aug[lr][q * 32 + lk * 8];
            bf16x8 al = *(const bf16x8*)&h_aug[lr][128 + q * 32 + lk * 8];
            acc0 = __builtin_amdgcn_mfma_f32_16x16x32_bf16(ah, bhi[0][q], acc0, 0, 0, 0);
            acc1 = __builtin_amdgcn_mfma_f32_16x16x32_bf16(ah, bhi[1][q], acc1, 0, 0, 0);
            acc2 = __builtin_amdgcn_mfma_f32_16x16x32_bf16(ah, bhi[2][q], acc2, 0, 0, 0);
            acc3 = __builtin_amdgcn_mfma_f32_16x16x32_bf16(ah, bhi[3][q], acc3, 0, 0, 0);
            acc0 = __builtin_amdgcn_mfma_f32_16x16x32_bf16(al, bhi[0][q], acc0, 0, 0, 0);
            acc1 = __builtin_amdgcn_mfma_f32_16x16x32_bf16(al, bhi[1][q], acc1, 0, 0, 0);
            acc2 = __builtin_amdgcn_mfma_f32_16x16x32_bf16(al, bhi[2][q], acc2, 0, 0, 0);
            acc3 = __builtin_amdgcn_mfma_f32_16x16x32_bf16(al, bhi[3][q], acc3, 0, 0, 0);
            acc0 = __builtin_amdgcn_mfma_f32_16x16x32_bf16(ah, blo[0][q], acc0, 0, 0, 0);
            acc1 = __builtin_amdgcn_mfma_f32_16x16x32_bf16(ah, blo[1][q], acc1, 0, 0, 0);
            acc2 = __builtin_amdgcn_mfma_f32_16x16x32_bf16(ah, blo[2][q], acc2, 0, 0, 0);
            acc3 = __builtin_amdgcn_mfma_f32_16x16x32_bf16(ah, blo[3][q], acc3, 0, 0, 0);
        }

        // activate (wave-uniform gate type) and publish to act LDS
        float gv0[4], gv1[4], gv2[4], gv3[4];
#pragma unroll
        for (int e = 0; e < 4; e++) {
            if (gtype == 2) {
                gv0[e] = fast_tanh(acc0[e]); gv1[e] = fast_tanh(acc1[e]);
                gv2[e] = fast_tanh(acc2[e]); gv3[e] = fast_tanh(acc3[e]);
            } else {
                gv0[e] = fast_sigmoid(acc0[e]); gv1[e] = fast_sigmoid(acc1[e]);
                gv2[e] = fast_sigmoid(acc2[e]); gv3[e] = fast_sigmoid(acc3[e]);
            }
        }
#pragma unroll
        for (int e = 0; e < 4; e++) {
            int r = 4 * lk + e;
            act[r][gbase + lr] = gv0[e];
            act[r][gbase + 16 + lr] = gv1[e];
            act[r][gbase + 32 + lr] = gv2[e];
            act[r][gbase + 48 + lr] = gv3[e];
        }
        __syncthreads();

        // phase B: c/h update, y store, republish h as bf16 hi/lo
#pragma unroll
        for (int p = 0; p < 4; p++) {
            int r = q4 * 4 + p;
            float iv = act[r][u];
            float fv = act[r][HS + u];
            float gg = act[r][2 * HS + u];
            float ov = act[r][3 * HS + u];
            c[p] = fmaf(fv, c[p], iv * gg);
            float hv = ov * fast_tanh(c[p]);
            y[((size_t)(b0 + r) * TT + t0 + t) * HS + u] = hv;
            ushort hb = f2bf(hv);
            h_aug[r][u] = hb;
            h_aug[r][128 + u] = f2bf(hv - bf2f(hb));
            if (t == Tc - 1) {
                hstate[(size_t)(b0 + r) * HS + u] = hv;
                cstate[(size_t)(b0 + r) * HS + u] = c[p];
            }
        }
        __syncthreads();

#pragma unroll
        for (int i = 0; i < 16; i++) cur[i] = nxt[i];
    }
}

// out[row] = dot(z2[row,:], W3[0,:]) + b3 — one wave per row
__global__ __launch_bounds__(256) void head_dot(
    const float* __restrict__ z2, const float* __restrict__ W3,
    const float* __restrict__ b3, float* __restrict__ out) {
    const int wave = threadIdx.x >> 6, lane = threadIdx.x & 63;
    const int row = blockIdx.x * 4 + wave;
    const float* zr = z2 + (size_t)row * HS;
    float v = zr[lane] * W3[lane] + zr[64 + lane] * W3[64 + lane];
#pragma unroll
    for (int m = 32; m >= 1; m >>= 1) v += __shfl_xor(v, m, 64);
    if (lane == 0) out[row] = v + b3[0];
}

extern "C" void kernel_launch(void* const* d_in, const int* in_sizes, int n_in,
                              void* d_out, int out_size, void* d_ws, size_t ws_size,
                              hipStream_t stream) {
    const float* x = (const float*)d_in[0];
    const float* h0 = (const float*)d_in[1];
    const float* c0 = (const float*)d_in[2];
    const float* Wih[3] = {(const float*)d_in[3], (const float*)d_in[7], (const float*)d_in[11]};
    const float* Whh[3] = {(const float*)d_in[4], (const float*)d_in[8], (const float*)d_in[12]};
    const float* bih[3] = {(const float*)d_in[5], (const float*)d_in[9], (const float*)d_in[13]};
    const float* bhh[3] = {(const float*)d_in[6], (const float*)d_in[10], (const float*)d_in[14]};
    const float* W1 = (const float*)d_in[15];
    const float* b1 = (const float*)d_in[16];
    const float* W2 = (const float*)d_in[17];
    const float* b2 = (const float*)d_in[18];
    const float* W3 = (const float*)d_in[19];
    const float* b3 = (const float*)d_in[20];
    float* outp = (float*)d_out;

    // workspace layout: y[B,T,H] | xW[B,Tc,4H] | hstate[B,H] | cstate[B,H]
    int Tc = TT;
    while (Tc > 8) {
        size_t need = ((size_t)BB * TT * HS + (size_t)BB * Tc * GS + 2 * (size_t)BB * HS) * 4;
        if (need <= ws_size) break;
        Tc >>= 1;
    }
    float* yb = (float*)d_ws;
    float* xw = yb + (size_t)BB * TT * HS;
    float* hs = xw + (size_t)BB * Tc * GS;
    float* cs = hs + (size_t)BB * HS;

    for (int l = 0; l < 3; ++l) {
        for (int t0 = 0; t0 < TT; t0 += Tc) {
            dim3 gp(BB * Tc / 128, GS / 64);
            if (l == 0)
                gemm2<XS, XS, GS, MODE_PROJ, false><<<gp, 256, 0, stream>>>(
                    x, nullptr, Wih[0], bih[0], bhh[0], xw, Tc, t0, 0);
            else
                gemm2<HS, 32, GS, MODE_PROJ, false><<<gp, 256, 0, stream>>>(
                    yb, nullptr, Wih[l], bih[l], bhh[l], xw, Tc, t0, 0);
            lstm_rec3<<<BB / BSUB, 512, 0, stream>>>(
                Whh[l], xw, h0 + (size_t)l * BB * HS, c0 + (size_t)l * BB * HS,
                hs, cs, yb, Tc, t0);
        }
    }

    // MLP head, row-chunked: z1 (local rows) lives in xw buffer
    const int totalRows = BB * TT;
    int Rc = BB * Tc * (GS / HS);
    if (Rc > totalRows) Rc = totalRows;
    for (int r0 = 0; r0 < totalRows; r0 += Rc) {
        dim3 gm(Rc / 128, HS / 64);
        gemm2<XS + HS, 28, HS, MODE_CONCAT, true><<<gm, 256, 0, stream>>>(
            x, yb, W1, b1, nullptr, xw, 0, r0, 0);
        gemm2<HS, 32, HS, MODE_FLAT, true><<<gm, 256, 0, stream>>>(
            xw, nullptr, W2, b2, nullptr, yb, 0, 0, r0);
    }
    head_dot<<<totalRows / 4, 256, 0, stream>>>(yb, W3, b3, outp);
}

// Round 4
// 3060.808 us; speedup vs baseline: 1.4949x; 1.4949x over previous
//
#include <hip/hip_runtime.h>
#include <hip/hip_bf16.h>

#define BB 256
#define TT 512
#define XS 40
#define HS 128
#define GS 512  // 4*HS

enum { MODE_PROJ = 0, MODE_FLAT = 1, MODE_CONCAT = 2 };

__device__ __forceinline__ float fast_sigmoid(float x) {
    return __frcp_rn(1.0f + __expf(-x));
}
__device__ __forceinline__ float fast_tanh(float x) {
    x = fminf(fmaxf(x, -15.0f), 15.0f);
    float e = __expf(2.0f * x);
    return (e - 1.0f) * __frcp_rn(e + 1.0f);
}

// ---------------- gemm3: A staged once, N-chunks looped in-block ----------------
// 512 threads, M-tile 128, N-chunk 64. at[k][m] k-major (8-way write conflict at
// staging only ~5% cost; reads conflict-free). W restaged per chunk (L2-hot).
template <int K, int NS, int MODE, bool RELU>
__global__ __launch_bounds__(512) void gemm3(
    const float* __restrict__ A, const float* __restrict__ A2,
    const float* __restrict__ W, const float* __restrict__ b1p,
    const float* __restrict__ b2p, float* __restrict__ out,
    int Tc, int t0, int ooff) {
    __shared__ float at[K][132];  // 132*4=528B row stride; 16B-aligned for b128
    __shared__ float wt[K][68];
    const int tid = threadIdx.x;
    const int row0 = blockIdx.x * 128;
    const int tx = tid & 15;   // n = nc*64 + tx*4 + j
    const int ty = tid >> 4;   // m = row0 + ty*4 + i

    // stage A once: coalesced global (consecutive k), transposed into at[k][m]
    for (int idx = tid; idx < 128 * K; idx += 512) {
        int m = idx / K, k = idx - m * K;
        int mg = row0 + m;
        float v;
        if (MODE == MODE_PROJ) {
            int b = mg / Tc, tt = mg - b * Tc;
            v = A[(size_t)(b * TT + t0 + tt) * K + k];
        } else if (MODE == MODE_FLAT) {
            v = A[(size_t)(mg + t0) * K + k];
        } else {
            int mgg = mg + t0;
            v = (k < XS) ? A[(size_t)mgg * XS + k] : A2[(size_t)mgg * HS + (k - XS)];
        }
        at[k][m] = v;
    }
    __syncthreads();

    for (int nc = 0; nc < NS / 64; ++nc) {
        // stage W chunk (64 rows x K), transposed into wt[k][n]
        for (int idx = tid; idx < 64 * K; idx += 512) {
            int n = idx / K, k = idx - n * K;
            wt[k][n] = W[(size_t)(nc * 64 + n) * K + k];
        }
        __syncthreads();

        float acc[4][4] = {};
#pragma unroll 4
        for (int k = 0; k < K; ++k) {
            float4 av = *(const float4*)&at[k][ty * 4];
            float4 wv = *(const float4*)&wt[k][tx * 4];
            float aa[4] = {av.x, av.y, av.z, av.w};
            float ww[4] = {wv.x, wv.y, wv.z, wv.w};
#pragma unroll
            for (int i = 0; i < 4; i++)
#pragma unroll
                for (int j = 0; j < 4; j++) acc[i][j] = fmaf(aa[i], ww[j], acc[i][j]);
        }

        int nb = nc * 64 + tx * 4;
        float4 bv = *(const float4*)&b1p[nb];
        if (MODE == MODE_PROJ) {
            float4 b2v = *(const float4*)&b2p[nb];
            bv.x += b2v.x; bv.y += b2v.y; bv.z += b2v.z; bv.w += b2v.w;
        }
#pragma unroll
        for (int i = 0; i < 4; i++) {
            int m = row0 + ty * 4 + i;
            size_t obase = (MODE == MODE_PROJ) ? (size_t)m * NS : (size_t)(m + ooff) * NS;
            float4 o;
            o.x = acc[i][0] + bv.x; o.y = acc[i][1] + bv.y;
            o.z = acc[i][2] + bv.z; o.w = acc[i][3] + bv.w;
            if (RELU) {
                o.x = fmaxf(o.x, 0.f); o.y = fmaxf(o.y, 0.f);
                o.z = fmaxf(o.z, 0.f); o.w = fmaxf(o.w, 0.f);
            }
            *(float4*)&out[obase + nb] = o;
        }
        __syncthreads();  // before restaging wt
    }
}

// ---------------- recurrence: round-2 structure + forced weight residency ----------------
#define WLOAD(i) float4 w##i = wr[i];
#define PIN4(i) asm volatile("" : "+v"(w##i.x), "+v"(w##i.y), "+v"(w##i.z), "+v"(w##i.w));
#define DOT(i)                                    \
    {                                             \
        float4 hv = h4[i];                        \
        s0 = fmaf(w##i.x, hv.x, s0);              \
        s1 = fmaf(w##i.y, hv.y, s1);              \
        s2 = fmaf(w##i.z, hv.z, s2);              \
        s3 = fmaf(w##i.w, hv.w, s3);              \
    }

__global__ __launch_bounds__(1024, 4) void lstm_rec4(
    const float* __restrict__ Whh, const float* __restrict__ xW,
    const float* __restrict__ h0, const float* __restrict__ c0,
    float* __restrict__ hstate, float* __restrict__ cstate,
    float* __restrict__ y, int Tc, int t0) {
    const int b = blockIdx.x;
    const int tid = threadIdx.x;
    const int gate = tid >> 1;   // 0..511
    const int half = tid & 1;    // which 64-chunk of the dot
    __shared__ __align__(16) float h_sh[HS];
    __shared__ float act[GS];

    const float4* wr = (const float4*)(Whh + (size_t)gate * HS + half * 64);
    WLOAD(0) WLOAD(1) WLOAD(2) WLOAD(3) WLOAD(4) WLOAD(5) WLOAD(6) WLOAD(7)
    WLOAD(8) WLOAD(9) WLOAD(10) WLOAD(11) WLOAD(12) WLOAD(13) WLOAD(14) WLOAD(15)

    float c = 0.0f;
    if (tid < HS) {
        float hv;
        if (t0 == 0) {
            hv = h0[(size_t)b * HS + tid];
            c = c0[(size_t)b * HS + tid];
        } else {
            hv = hstate[(size_t)b * HS + tid];
            c = cstate[(size_t)b * HS + tid];
        }
        h_sh[tid] = hv;
    }
    __syncthreads();

    const float* xWrow = xW + (size_t)b * Tc * GS;
    float* yrow = y + ((size_t)b * TT + t0) * HS;
    const float4* h4 = (const float4*)h_sh + half * 16;
    const int gtype = gate >> 7;  // 0=i 1=f 2=g 3=o (wave-uniform)

    float a_cur = (half == 0) ? xWrow[gate] : 0.0f;  // t = 0 prefetch

    for (int t = 0; t < Tc; ++t) {
        // pin weights in VGPRs: asm "modifies" them each iter -> reload illegal
        PIN4(0) PIN4(1) PIN4(2) PIN4(3) PIN4(4) PIN4(5) PIN4(6) PIN4(7)
        PIN4(8) PIN4(9) PIN4(10) PIN4(11) PIN4(12) PIN4(13) PIN4(14) PIN4(15)

        int tn = (t + 1 < Tc) ? t + 1 : t;
        float a_nxt = (half == 0) ? xWrow[(size_t)tn * GS + gate] : 0.0f;

        float s0 = 0.f, s1 = 0.f, s2 = 0.f, s3 = 0.f;
        DOT(0) DOT(1) DOT(2) DOT(3) DOT(4) DOT(5) DOT(6) DOT(7)
        DOT(8) DOT(9) DOT(10) DOT(11) DOT(12) DOT(13) DOT(14) DOT(15)
        float v = (s0 + s1) + (s2 + s3);
        v += __shfl_xor(v, 1);  // partner lane holds other half of the dot
        if (half == 0) {
            v += a_cur;
            act[gate] = (gtype == 2) ? fast_tanh(v) : fast_sigmoid(v);
        }
        __syncthreads();
        if (tid < HS) {
            float iv = act[tid], fv = act[HS + tid], gg = act[2 * HS + tid], ov = act[3 * HS + tid];
            c = fmaf(fv, c, iv * gg);
            float hv = ov * fast_tanh(c);
            h_sh[tid] = hv;
            yrow[(size_t)t * HS + tid] = hv;
        }
        __syncthreads();
        a_cur = a_nxt;
    }
    if (tid < HS) {
        hstate[(size_t)b * HS + tid] = h_sh[tid];
        cstate[(size_t)b * HS + tid] = c;
    }
}

// out[row] = dot(z2[row,:], W3[0,:]) + b3 — one wave per row
__global__ __launch_bounds__(256) void head_dot(
    const float* __restrict__ z2, const float* __restrict__ W3,
    const float* __restrict__ b3, float* __restrict__ out) {
    const int wave = threadIdx.x >> 6, lane = threadIdx.x & 63;
    const int row = blockIdx.x * 4 + wave;
    const float* zr = z2 + (size_t)row * HS;
    float v = zr[lane] * W3[lane] + zr[64 + lane] * W3[64 + lane];
#pragma unroll
    for (int m = 32; m >= 1; m >>= 1) v += __shfl_xor(v, m, 64);
    if (lane == 0) out[row] = v + b3[0];
}

extern "C" void kernel_launch(void* const* d_in, const int* in_sizes, int n_in,
                              void* d_out, int out_size, void* d_ws, size_t ws_size,
                              hipStream_t stream) {
    const float* x = (const float*)d_in[0];
    const float* h0 = (const float*)d_in[1];
    const float* c0 = (const float*)d_in[2];
    const float* Wih[3] = {(const float*)d_in[3], (const float*)d_in[7], (const float*)d_in[11]};
    const float* Whh[3] = {(const float*)d_in[4], (const float*)d_in[8], (const float*)d_in[12]};
    const float* bih[3] = {(const float*)d_in[5], (const float*)d_in[9], (const float*)d_in[13]};
    const float* bhh[3] = {(const float*)d_in[6], (const float*)d_in[10], (const float*)d_in[14]};
    const float* W1 = (const float*)d_in[15];
    const float* b1 = (const float*)d_in[16];
    const float* W2 = (const float*)d_in[17];
    const float* b2 = (const float*)d_in[18];
    const float* W3 = (const float*)d_in[19];
    const float* b3 = (const float*)d_in[20];
    float* outp = (float*)d_out;

    // workspace layout: y[B,T,H] | xW[B,Tc,4H] | hstate[B,H] | cstate[B,H]
    int Tc = TT;
    while (Tc > 8) {
        size_t need = ((size_t)BB * TT * HS + (size_t)BB * Tc * GS + 2 * (size_t)BB * HS) * 4;
        if (need <= ws_size) break;
        Tc >>= 1;
    }
    float* yb = (float*)d_ws;
    float* xw = yb + (size_t)BB * TT * HS;
    float* hs = xw + (size_t)BB * Tc * GS;
    float* cs = hs + (size_t)BB * HS;

    for (int l = 0; l < 3; ++l) {
        for (int t0 = 0; t0 < TT; t0 += Tc) {
            dim3 gp(BB * Tc / 128);
            if (l == 0)
                gemm3<XS, GS, MODE_PROJ, false><<<gp, 512, 0, stream>>>(
                    x, nullptr, Wih[0], bih[0], bhh[0], xw, Tc, t0, 0);
            else
                gemm3<HS, GS, MODE_PROJ, false><<<gp, 512, 0, stream>>>(
                    yb, nullptr, Wih[l], bih[l], bhh[l], xw, Tc, t0, 0);
            lstm_rec4<<<BB, 1024, 0, stream>>>(Whh[l], xw,
                                               h0 + (size_t)l * BB * HS, c0 + (size_t)l * BB * HS,
                                               hs, cs, yb, Tc, t0);
        }
    }

    // MLP head, row-chunked: z1 (local rows) lives in xw buffer
    const int totalRows = BB * TT;
    int Rc = BB * Tc * (GS / HS);
    if (Rc > totalRows) Rc = totalRows;
    for (int r0 = 0; r0 < totalRows; r0 += Rc) {
        dim3 gm(Rc / 128);
        gemm3<XS + HS, HS, MODE_CONCAT, true><<<gm, 512, 0, stream>>>(
            x, yb, W1, b1, nullptr, xw, 0, r0, 0);
        gemm3<HS, HS, MODE_FLAT, true><<<gm, 512, 0, stream>>>(
            xw, nullptr, W2, b2, nullptr, yb, 0, 0, r0);
    }
    head_dot<<<totalRows / 4, 256, 0, stream>>>(yb, W3, b3, outp);
}